// Round 7
// baseline (176.243 us; speedup 1.0000x reference)
//
#include <hip/hip_runtime.h>
#include <stdint.h>

#define N_ANCH 36864
#define KCAND  4096
#define NBUCK  384
#define NSEL   300
#define NGT    64
#define NBATCH 16
#define SCORE_THRESH 0.908f

typedef unsigned long long u64;

__device__ __forceinline__ float clip01(float v) { return fminf(fmaxf(v, 0.0f), 1.0f); }

// ---- Exact division-free suppression, branchless accumulation form ----
// Reference decision: RN(inter / D) >= 0.5, D = ((aa+ab) - inter) + 1e-7f.
//   dt = 0.5*D (exact),  r = RN(dt*(1-2^-23)) < dt.
//   inter >= dt  => q >= 0.5 certainly;  inter < r => q < 0.5 certainly;
//   inter in [r, dt) -> uncertain band (width ~1 ulp) -> exact division rerun.
// Sign-exact: RN(inter - dt) has the sign of the exact difference (Sterbenz
// for dt/2<=inter<=2dt; larger gaps preserve sign; x-x=+0), so
//   m  = max(inter - dt)  >= 0  <=> exists certain-suppress
//   mm = max(inter - r)   >= 0 && m < 0  <=> only uncertain-band hits
// One __any AFTER the loop; loop body is branch-free.  Duplicate tests of
// real accepted boxes are idempotent under max => clamped prefetch is exact.
__device__ __forceinline__ void supp_acc(const float4 A, float Aa, const float4 B, float ab,
                                         float& m, float& mm) {
    float y1 = fmaxf(A.x, B.x);
    float x1 = fmaxf(A.y, B.y);
    float y2 = fminf(A.z, B.z);
    float x2 = fminf(A.w, B.w);
    float ih = fmaxf(y2 - y1, 0.0f);
    float iw = fmaxf(x2 - x1, 0.0f);
    float inter = ih * iw;
    float D  = ((Aa + ab) - inter) + 1e-7f;   // exact reference op order
    float dt = 0.5f * D;                      // exact (D >= 1e-7, no subnormals)
    float r  = fmaf(dt, -0x1p-23f, dt);
    m  = fmaxf(m,  inter - dt);
    mm = fmaxf(mm, inter - r);
}

__device__ __forceinline__ bool supp_div(const float4 A, float Aa, const float4 B, float ab) {
    float y1 = fmaxf(A.x, B.x);
    float x1 = fmaxf(A.y, B.y);
    float y2 = fminf(A.z, B.z);
    float x2 = fminf(A.w, B.w);
    float ih = fmaxf(y2 - y1, 0.0f);
    float iw = fmaxf(x2 - x1, 0.0f);
    float inter = ih * iw;
    float D = ((Aa + ab) - inter) + 1e-7f;
    return (inter / D) >= 0.5f;               // exact IEEE decision
}

// single test: certain flag + uncertain flag (for intra-chunk bit masks)
__device__ __forceinline__ void supp_bit(const float4 A, float Aa, const float4 B, float ab,
                                         bool& sj, bool& uj) {
    float y1 = fmaxf(A.x, B.x);
    float x1 = fmaxf(A.y, B.y);
    float y2 = fminf(A.z, B.z);
    float x2 = fminf(A.w, B.w);
    float ih = fmaxf(y2 - y1, 0.0f);
    float iw = fmaxf(x2 - x1, 0.0f);
    float inter = ih * iw;
    float D  = ((Aa + ab) - inter) + 1e-7f;
    float dt = 0.5f * D;
    float r  = fmaf(dt, -0x1p-23f, dt);
    sj = inter >= dt;
    uj = (inter >= r) && !sj;
}

__device__ __forceinline__ float4 decode_one(const float4 a4, const float4 d4) {
    float ah = a4.z - a4.x, aw = a4.w - a4.y;
    float acy = a4.x + 0.5f * ah, acx = a4.y + 0.5f * aw;
    float h = expf(d4.z) * ah, w = expf(d4.w) * aw;
    float cy = d4.x * ah + acy, cx = d4.y * aw + acx;
    float y1 = cy - 0.5f * h, x1 = cx - 0.5f * w;
    return make_float4(y1, x1, y1 + h, x1 + w);
}

// scores in (0.908, 1.0) all share exponent 0x7E -> ulp-linear bucket digit,
// ascending digit == descending score. width 4096 ulps -> lambda ~9 per bucket.
__device__ __forceinline__ int bucket_of(float s) {
    unsigned d = (0x3F800000u - __float_as_uint(s)) >> 12;
    return (d < NBUCK) ? (int)d : (NBUCK - 1);
}

__global__ __launch_bounds__(1024)
void roi_bbox_kernel(const float* __restrict__ deltas,
                     const float* __restrict__ labels,
                     const float* __restrict__ anchors,
                     const float* __restrict__ gt,
                     float* __restrict__ out)
{
    __shared__ u64    s_sorted[KCAND];   // 32 KB, bucket-ordered then rank-sorted
    __shared__ int    s_hist[NBUCK];
    __shared__ int    s_cur[NBUCK];
    __shared__ int    s_base[NBUCK + 1];
    __shared__ float4 s_accB[NSEL + 4];  // accepted raw (unclipped) boxes, pop order
    __shared__ float4 s_cbox[2][128];    // double-buffered PAIR boxes (128/pair)
    __shared__ unsigned int s_pre[2][128];   // suppression flags per candidate
    __shared__ unsigned int s_gmlo[2][128];  // intra-half 64-bit masks (lo)
    __shared__ unsigned int s_gmhi[2][128];  // intra-half 64-bit masks (hi)
    __shared__ int   s_accCount;
    __shared__ float s_merged[NSEL];
    __shared__ int   s_gtbest[NSEL];
    __shared__ float4 s_gt[NGT];
    __shared__ int   s_selidx[64];

    const int b    = blockIdx.x;
    const int tid  = threadIdx.x;
    const int lane = tid & 63;
    const int wv   = tid >> 6;
    const float*  sc    = labels + (size_t)b * N_ANCH;
    const float4* sc4   = (const float4*)sc;
    const float4* anch4 = (const float4*)(anchors + (size_t)b * N_ANCH * 4);
    const float4* del4  = (const float4*)(deltas  + (size_t)b * N_ANCH * 4);
    const float4* gt4   = (const float4*)(gt + (size_t)b * NGT * 4);

    if (tid < NBUCK) s_hist[tid] = 0;
    if (tid == 0) s_accCount = 0;
    __syncthreads();

    // ---- Phase A1: bucket histogram (float4-vectorized) ----
    for (int i = tid; i < N_ANCH / 4; i += 1024) {
        float4 v = sc4[i];
        float vv[4] = {v.x, v.y, v.z, v.w};
        #pragma unroll
        for (int k = 0; k < 4; ++k)
            if (vv[k] > SCORE_THRESH) atomicAdd(&s_hist[bucket_of(vv[k])], 1);
    }
    __syncthreads();

    // ---- exclusive scan of 384 counts (wave 0: 6 counts/lane + shfl scan) ----
    if (tid < 64) {
        int c[6]; int sum = 0;
        #pragma unroll
        for (int k = 0; k < 6; ++k) { c[k] = s_hist[tid * 6 + k]; sum += c[k]; }
        int inc = sum;
        #pragma unroll
        for (int off = 1; off < 64; off <<= 1) {
            int v = __shfl_up(inc, off);
            if (lane >= off) inc += v;
        }
        int excl = inc - sum;
        #pragma unroll
        for (int k = 0; k < 6; ++k) {
            s_base[tid * 6 + k] = excl;
            s_cur[tid * 6 + k]  = excl;
            excl += c[k];
        }
        if (tid == 63) s_base[NBUCK] = excl;
    }
    __syncthreads();

    // ---- Phase A2: scatter keys into bucket regions (L2-hot reload, vectorized) ----
    for (int i = tid; i < N_ANCH / 4; i += 1024) {
        float4 v = sc4[i];
        float vv[4] = {v.x, v.y, v.z, v.w};
        #pragma unroll
        for (int k = 0; k < 4; ++k) {
            float sval = vv[k];
            if (sval > SCORE_THRESH) {
                int idx = i * 4 + k;
                int pos = atomicAdd(&s_cur[bucket_of(sval)], 1);
                if (pos < KCAND)
                    s_sorted[pos] = ((u64)__float_as_uint(sval) << 32)
                                  | (u64)(0xFFFFFFFFu - (unsigned)idx);
            }
        }
    }
    __syncthreads();

    // ---- per-bucket rank sort (one wave per bucket, no barriers inside) ----
    for (int bk = wv; bk < NBUCK; bk += 16) {
        int lo = s_base[bk], hi = s_base[bk + 1];
        if (lo > KCAND) lo = KCAND;
        if (hi > KCAND) hi = KCAND;
        int n = hi - lo;
        if (n <= 1) continue;
        u64 mykey = (lane < n) ? s_sorted[lo + lane] : 0ull;
        int rank = 0;
        for (int j = 0; j < n; ++j) {          // broadcast reads, conflict-free
            u64 kj = s_sorted[lo + j];
            rank += (kj > mykey);
        }
        if (lane < n) s_sorted[lo + rank] = mykey;  // in-wave: reads precede write
    }
    __syncthreads();

    int M = s_base[NBUCK]; if (M > KCAND) M = KCAND;

    // ---- pre-loop: decode pair 0 (128 candidates), zero parity-0 masks ----
    if (tid < 128) {
        s_pre[0][tid] = 0u; s_gmlo[0][tid] = 0u; s_gmhi[0][tid] = 0u;
        if (tid < M) {
            u64 key = s_sorted[tid];
            int idx = (int)(0xFFFFFFFFu - (unsigned)(key & 0xFFFFFFFFull));
            s_cbox[0][tid] = decode_one(anch4[idx], del4[idx]);
        }
    }
    __syncthreads();

    // ---- Phase B: greedy NMS, 128-candidate pairs, 2 barriers/pair ----
    // R1: wv1 decode/zero next; waves{0,2..15} pipelined long-loop both halves;
    //     waves 2..9 intra-half1 (stride 8); waves 10..15 intra-half2 (stride 6).
    // R2: wave0 serial: resolve half1 -> lane-parallel cross-tests (c1 vs new
    //     accepts, in-register) -> resolve half2.
    int accCount = 0;
    for (int start = 0; start < M && accCount < NSEL; start += 128) {
        int p  = (start >> 7) & 1;
        int C  = M - start; if (C > 128) C = 128;
        int C1 = C < 64 ? C : 64;
        int C2 = C - C1;                       // candidates in half2 (0..64)
        int c  = lane;
        int sidx15 = (wv == 0) ? 0 : (wv - 1); // 15-slice id for waves {0,2..15}

        float4 c0 = make_float4(0.f,0.f,0.f,0.f), c1 = make_float4(0.f,0.f,0.f,0.f);
        float a0 = 0.f, a1 = 0.f;

        // ---------------- Region 1 ----------------
        if (wv == 1) {
            s_pre[p^1][c]       = 0u; s_pre[p^1][64+c]  = 0u;
            s_gmlo[p^1][c]      = 0u; s_gmlo[p^1][64+c] = 0u;
            s_gmhi[p^1][c]      = 0u; s_gmhi[p^1][64+c] = 0u;
            int ni0 = start + 128 + c;
            int ni1 = start + 192 + c;
            if (ni0 < M) {
                u64 key = s_sorted[ni0];
                int idx = (int)(0xFFFFFFFFu - (unsigned)(key & 0xFFFFFFFFull));
                s_cbox[p^1][c] = decode_one(anch4[idx], del4[idx]);
            }
            if (ni1 < M) {
                u64 key = s_sorted[ni1];
                int idx = (int)(0xFFFFFFFFu - (unsigned)(key & 0xFFFFFFFFull));
                s_cbox[p^1][64+c] = decode_one(anch4[idx], del4[idx]);
            }
        } else {
            // candidate registers (zero-box for invalid lanes: inter==0 always,
            // never suppressed, never triggers the uncertain band)
            if (c < C1) c0 = s_cbox[p][c];
            if (c < C2) c1 = s_cbox[p][64+c];
            a0 = (c0.z - c0.x) * (c0.w - c0.y);
            a1 = (c1.z - c1.x) * (c1.w - c1.y);

            // pipelined branchless long-loop: prefetch next iteration's boxes
            // with CLAMPED indices (duplicate tests of real accepted boxes are
            // exact no-ops under max-accumulation).
            float m0 = -1.f, mm0 = -1.f, m1 = -1.f, mm1 = -1.f;
            if (accCount > 0) {
                int last = accCount - 1;
                int i0 = sidx15      < last ? sidx15      : last;
                int i1 = sidx15 + 15 < last ? sidx15 + 15 : last;
                float4 A0 = s_accB[i0];
                float4 A1 = s_accB[i1];
                for (int a = sidx15; a < accCount; a += 30) {
                    int j0 = a + 30 < last ? a + 30 : last;
                    int j1 = a + 45 < last ? a + 45 : last;
                    float4 N0 = s_accB[j0];          // in flight during compute
                    float4 N1 = s_accB[j1];
                    float Aa0 = (A0.z - A0.x) * (A0.w - A0.y);
                    float Aa1 = (A1.z - A1.x) * (A1.w - A1.y);
                    supp_acc(A0, Aa0, c0, a0, m0, mm0);
                    supp_acc(A0, Aa0, c1, a1, m1, mm1);
                    supp_acc(A1, Aa1, c0, a0, m0, mm0);
                    supp_acc(A1, Aa1, c1, a1, m1, mm1);
                    A0 = N0; A1 = N1;
                }
            }
            bool s0 = (m0 >= 0.f), s1 = (m1 >= 0.f);
            bool rr = ((m0 < 0.f) && (mm0 >= 0.f)) || ((m1 < 0.f) && (mm1 >= 0.f));
            if (__builtin_expect(__any((int)rr), 0)) {
                for (int a2 = sidx15; a2 < accCount; a2 += 15) {
                    float4 A = s_accB[a2];
                    float Aa = (A.z - A.x) * (A.w - A.y);
                    s0 |= supp_div(A, Aa, c0, a0);
                    s1 |= supp_div(A, Aa, c1, a1);
                }
            }
            if (s0 && c < C1) s_pre[p][c]      = 1u;   // same-value race, benign
            if (s1 && c < C2) s_pre[p][64 + c] = 1u;

            if (wv >= 2 && wv <= 9) {
                // intra half1: 8 slices, branchless + deferred rare rerun
                int s8 = wv - 2;
                if (c < C1) {
                    unsigned mlo = 0u, mhi = 0u;
                    bool ur = false;
                    for (int j = s8; j < c; j += 8) {        // j wave-uniform
                        float4 bj = s_cbox[p][j];
                        float  aj = (bj.z - bj.x) * (bj.w - bj.y);
                        bool sj, uj;
                        supp_bit(bj, aj, c0, a0, sj, uj);
                        ur |= uj;
                        unsigned bit = sj ? 1u : 0u;
                        if (j < 32) mlo |= bit << j; else mhi |= bit << (j - 32);
                    }
                    if (__builtin_expect(__any((int)ur), 0)) {
                        for (int j = s8; j < c; j += 8) {
                            float4 bj = s_cbox[p][j];
                            float  aj = (bj.z - bj.x) * (bj.w - bj.y);
                            unsigned bit = supp_div(bj, aj, c0, a0) ? 1u : 0u;
                            if (j < 32) mlo |= bit << j; else mhi |= bit << (j - 32);
                        }
                    }
                    if (mlo) atomicOr(&s_gmlo[p][c], mlo);
                    if (mhi) atomicOr(&s_gmhi[p][c], mhi);
                }
            } else if (wv >= 10) {
                // intra half2: 6 slices (waves 10..15)
                int s6 = wv - 10;
                if (c < C2) {
                    unsigned mlo = 0u, mhi = 0u;
                    bool ur = false;
                    for (int jj = s6; jj < c; jj += 6) {
                        float4 bj = s_cbox[p][64 + jj];
                        float  aj = (bj.z - bj.x) * (bj.w - bj.y);
                        bool sj, uj;
                        supp_bit(bj, aj, c1, a1, sj, uj);
                        ur |= uj;
                        unsigned bit = sj ? 1u : 0u;
                        if (jj < 32) mlo |= bit << jj; else mhi |= bit << (jj - 32);
                    }
                    if (__builtin_expect(__any((int)ur), 0)) {
                        for (int jj = s6; jj < c; jj += 6) {
                            float4 bj = s_cbox[p][64 + jj];
                            float  aj = (bj.z - bj.x) * (bj.w - bj.y);
                            unsigned bit = supp_div(bj, aj, c1, a1) ? 1u : 0u;
                            if (jj < 32) mlo |= bit << jj; else mhi |= bit << (jj - 32);
                        }
                    }
                    if (mlo) atomicOr(&s_gmlo[p][64 + c], mlo);
                    if (mhi) atomicOr(&s_gmhi[p][64 + c], mhi);
                }
            }
        }
        __syncthreads();

        // ---------------- Region 2: wave 0 resolves both halves ----------------
        if (tid < 64) {
            // resolve half1
            u64 mymask = ((u64)s_gmhi[p][tid] << 32) | (u64)s_gmlo[p][tid];
            bool alive = (tid < C1) && (s_pre[p][tid] == 0u);
            u64 accbits = 0ull, done = 0ull;
            int room = NSEL - accCount;
            int na = 0;
            while (na < room) {
                u64 am  = __ballot(alive);
                u64 rem = am & ~done;
                if (!rem) break;
                int l = __ffsll(rem) - 1;
                done = (2ull << l) - 1ull;
                accbits |= (1ull << l);
                ++na;
                if ((mymask >> l) & 1ull) alive = false;
            }
            if ((accbits >> tid) & 1ull) {
                int rank = __popcll(accbits & ((1ull << tid) - 1ull));
                s_accB[accCount + rank] = c0;          // own register == own candidate
            }
            int acc1 = accCount + __popcll(accbits);

            // cross-tests: this lane's half2 candidate vs half1's new accepts
            // (lane-parallel, uniform loop; s_accB writes above are same-wave)
            float m1b = -1.f, mm1b = -1.f;
            for (int a3 = accCount; a3 < acc1; ++a3) {
                float4 A = s_accB[a3];
                float Aa = (A.z - A.x) * (A.w - A.y);
                supp_acc(A, Aa, c1, a1, m1b, mm1b);
            }
            bool cross = (m1b >= 0.f);
            bool rr2 = (m1b < 0.f) && (mm1b >= 0.f);
            if (__builtin_expect(__any((int)rr2), 0)) {
                for (int a3 = accCount; a3 < acc1; ++a3) {
                    float4 A = s_accB[a3];
                    float Aa = (A.z - A.x) * (A.w - A.y);
                    cross |= supp_div(A, Aa, c1, a1);
                }
            }

            // resolve half2
            u64 mymask2 = ((u64)s_gmhi[p][64+tid] << 32) | (u64)s_gmlo[p][64+tid];
            bool alive2 = (tid < C2) && (s_pre[p][64+tid] == 0u) && !cross;
            u64 accbits2 = 0ull; done = 0ull;
            int room2 = NSEL - acc1;
            na = 0;
            while (na < room2) {
                u64 am  = __ballot(alive2);
                u64 rem = am & ~done;
                if (!rem) break;
                int l = __ffsll(rem) - 1;
                done = (2ull << l) - 1ull;
                accbits2 |= (1ull << l);
                ++na;
                if ((mymask2 >> l) & 1ull) alive2 = false;
            }
            if ((accbits2 >> tid) & 1ull) {
                int rank = __popcll(accbits2 & ((1ull << tid) - 1ull));
                s_accB[acc1 + rank] = c1;
            }
            if (tid == 0) s_accCount = acc1 + __popcll(accbits2);
        }
        __syncthreads();
        accCount = s_accCount;
    }

    // ---- Phase C: select_rois ----
    if (tid < NGT) s_gt[tid] = gt4[tid];
    __syncthreads();

    if (tid < NSEL) {
        float4 bx;
        if (tid < accCount) {
            float4 r = s_accB[tid];
            bx = make_float4(clip01(r.x), clip01(r.y), clip01(r.z), clip01(r.w));
        } else bx = make_float4(0.f, 0.f, 0.f, 0.f);
        float aa = (bx.z - bx.x) * (bx.w - bx.y);
        float best = -1e38f; int bi = 0;
        for (int g = 0; g < NGT; ++g) {
            float4 gb = s_gt[g];
            float y1 = fmaxf(bx.x, gb.x);
            float x1 = fmaxf(bx.y, gb.y);
            float y2 = fminf(bx.z, gb.z);
            float x2 = fminf(bx.w, gb.w);
            float ih = fmaxf(y2 - y1, 0.0f);
            float iw = fmaxf(x2 - x1, 0.0f);
            float inter = ih * iw;
            float ab = (gb.z - gb.x) * (gb.w - gb.y);
            float iou = inter / (aa + ab - inter + 1e-7f);
            if (iou > best) { best = iou; bi = g; }   // first-occurrence argmax
        }
        s_merged[tid] = best;
        s_gtbest[tid] = bi;
    }
    __syncthreads();

    // stable top-64 via rank selection: rank = #{j: v_j > v_i || (v_j==v_i && j<i)}
    if (tid < NSEL) {
        float v = s_merged[tid];
        int rank = 0;
        for (int j = 0; j < NSEL; ++j) {
            float u = s_merged[j];
            rank += (u > v) || (u == v && j < tid);
        }
        if (rank < 64) s_selidx[rank] = tid;
    }
    __syncthreads();

    // ---- outputs ----
    float* outIdx = out + (size_t)NBATCH * 128 * 4;   // 8192 box floats first
    if (tid < 256) {
        int r = tid >> 2, cc = tid & 3;
        int i = s_selidx[r];
        float val = 0.0f;
        if (i < accCount) {
            const float* p = (const float*)&s_accB[i];
            val = clip01(p[cc]);
        }
        out[((size_t)b * 128 + r) * 4 + cc] = val;
    } else if (tid < 512) {
        int j = tid - 256;
        out[((size_t)b * 128 + 64) * 4 + j] = 0.0f;   // TOTAL_NEG zero boxes
    } else if (tid < 576) {
        int r = tid - 512;
        outIdx[b * 64 + r] = (float)s_gtbest[s_selidx[r]];
    }
}

extern "C" void kernel_launch(void* const* d_in, const int* in_sizes, int n_in,
                              void* d_out, int out_size, void* d_ws, size_t ws_size,
                              hipStream_t stream) {
    const float* deltas  = (const float*)d_in[0];
    const float* labels  = (const float*)d_in[1];
    const float* anchors = (const float*)d_in[2];
    const float* gt      = (const float*)d_in[3];
    float* out = (float*)d_out;
    roi_bbox_kernel<<<NBATCH, 1024, 0, stream>>>(deltas, labels, anchors, gt, out);
}

// Round 8
// 156.136 us; speedup vs baseline: 1.1288x; 1.1288x over previous
//
#include <hip/hip_runtime.h>
#include <stdint.h>

#define N_ANCH 36864
#define KCAND  4096
#define NBUCK  384
#define NSEL   300
#define NGT    64
#define NBATCH 16
#define SCORE_THRESH 0.908f
// conservative uncertain-band threshold: dt <= 0.75 here => dt*2^-23 <= 9e-8 << 4e-7
#define BAND (-4e-7f)

typedef unsigned long long u64;

__device__ __forceinline__ float clip01(float v) { return fminf(fmaxf(v, 0.0f), 1.0f); }

// ---- Exact division-free suppression, single-accumulator form ----
// Reference decision: RN(inter / D) >= 0.5, D = ((aa+ab) - inter) + 1e-7f.
// dd = RN(inter - 0.5*D) via fma (0.5*D exact, fma rounds once -> == inter-dt).
// Sign-exact (Sterbenz / big-gap / x-x=+0):
//   dd >= 0                －> q >= 0.5 certainly
//   dd <  -dt*2^-23        -> q <  0.5 certainly
//   dd in [-dt*2^-23, 0)   -> uncertain 1-ulp band -> exact division rerun.
// m = max(dd) over pairs: m >= 0 <=> exists certain-suppress; rerun iff
// m in [BAND, 0) with BAND <= -dt*2^-23 for ALL pairs (conservative superset;
// false rerun just re-divides exactly). Duplicate tests idempotent under max.
__device__ __forceinline__ void supp_acc(const float4 A, float Aa, const float4 B, float ab,
                                         float& m) {
    float y1 = fmaxf(A.x, B.x);
    float x1 = fmaxf(A.y, B.y);
    float y2 = fminf(A.z, B.z);
    float x2 = fminf(A.w, B.w);
    float ih = fmaxf(y2 - y1, 0.0f);
    float iw = fmaxf(x2 - x1, 0.0f);
    float inter = ih * iw;
    float D  = ((Aa + ab) - inter) + 1e-7f;   // exact reference op order
    m = fmaxf(m, fmaf(-0.5f, D, inter));      // == RN(inter - dt), sign-exact
}

__device__ __forceinline__ bool supp_div(const float4 A, float Aa, const float4 B, float ab) {
    float y1 = fmaxf(A.x, B.x);
    float x1 = fmaxf(A.y, B.y);
    float y2 = fminf(A.z, B.z);
    float x2 = fminf(A.w, B.w);
    float ih = fmaxf(y2 - y1, 0.0f);
    float iw = fmaxf(x2 - x1, 0.0f);
    float inter = ih * iw;
    float D = ((Aa + ab) - inter) + 1e-7f;
    return (inter / D) >= 0.5f;               // exact IEEE decision
}

// single test: certain flag + uncertain flag (for intra-chunk bit masks)
__device__ __forceinline__ void supp_bit(const float4 A, float Aa, const float4 B, float ab,
                                         bool& sj, bool& uj) {
    float y1 = fmaxf(A.x, B.x);
    float x1 = fmaxf(A.y, B.y);
    float y2 = fminf(A.z, B.z);
    float x2 = fminf(A.w, B.w);
    float ih = fmaxf(y2 - y1, 0.0f);
    float iw = fmaxf(x2 - x1, 0.0f);
    float inter = ih * iw;
    float D  = ((Aa + ab) - inter) + 1e-7f;
    float dd = fmaf(-0.5f, D, inter);
    sj = dd >= 0.0f;
    uj = (dd >= BAND) && !sj;
}

__device__ __forceinline__ float4 decode_one(const float4 a4, const float4 d4) {
    float ah = a4.z - a4.x, aw = a4.w - a4.y;
    float acy = a4.x + 0.5f * ah, acx = a4.y + 0.5f * aw;
    float h = expf(d4.z) * ah, w = expf(d4.w) * aw;
    float cy = d4.x * ah + acy, cx = d4.y * aw + acx;
    float y1 = cy - 0.5f * h, x1 = cx - 0.5f * w;
    return make_float4(y1, x1, y1 + h, x1 + w);
}

// scores in (0.908, 1.0) all share exponent 0x7E -> ulp-linear bucket digit,
// ascending digit == descending score. width 4096 ulps -> lambda ~9 per bucket.
__device__ __forceinline__ int bucket_of(float s) {
    unsigned d = (0x3F800000u - __float_as_uint(s)) >> 12;
    return (d < NBUCK) ? (int)d : (NBUCK - 1);
}

__global__ __launch_bounds__(1024)
void roi_bbox_kernel(const float* __restrict__ deltas,
                     const float* __restrict__ labels,
                     const float* __restrict__ anchors,
                     const float* __restrict__ gt,
                     float* __restrict__ out)
{
    __shared__ u64    s_sorted[KCAND];   // 32 KB, bucket-ordered then rank-sorted
    __shared__ int    s_hist[NBUCK];
    __shared__ int    s_cur[NBUCK];
    __shared__ int    s_base[NBUCK + 1];
    __shared__ float4 s_accB[NSEL + 4];  // accepted raw (unclipped) boxes, pop order
    __shared__ float  s_accA[NSEL + 4];  // accepted areas (written once at accept)
    __shared__ float4 s_cbox[2][128];    // double-buffered PAIR boxes (128/pair)
    __shared__ float  s_carea[2][128];   // their areas (written at decode)
    __shared__ unsigned int s_pre[2][128];   // suppression flags per candidate
    __shared__ unsigned int s_gmlo[2][128];  // intra-half 64-bit masks (lo)
    __shared__ unsigned int s_gmhi[2][128];  // intra-half 64-bit masks (hi)
    __shared__ int   s_accCount;
    __shared__ float s_merged[NSEL];
    __shared__ int   s_gtbest[NSEL];
    __shared__ float4 s_gt[NGT];
    __shared__ int   s_selidx[64];

    const int b    = blockIdx.x;
    const int tid  = threadIdx.x;
    const int lane = tid & 63;
    const int wv   = tid >> 6;
    const float*  sc    = labels + (size_t)b * N_ANCH;
    const float4* sc4   = (const float4*)sc;
    const float4* anch4 = (const float4*)(anchors + (size_t)b * N_ANCH * 4);
    const float4* del4  = (const float4*)(deltas  + (size_t)b * N_ANCH * 4);
    const float4* gt4   = (const float4*)(gt + (size_t)b * NGT * 4);

    if (tid < NBUCK) s_hist[tid] = 0;
    if (tid == 0) s_accCount = 0;
    __syncthreads();

    // ---- Phase A1: bucket histogram (float4-vectorized) ----
    for (int i = tid; i < N_ANCH / 4; i += 1024) {
        float4 v = sc4[i];
        float vv[4] = {v.x, v.y, v.z, v.w};
        #pragma unroll
        for (int k = 0; k < 4; ++k)
            if (vv[k] > SCORE_THRESH) atomicAdd(&s_hist[bucket_of(vv[k])], 1);
    }
    __syncthreads();

    // ---- exclusive scan of 384 counts (wave 0: 6 counts/lane + shfl scan) ----
    if (tid < 64) {
        int c[6]; int sum = 0;
        #pragma unroll
        for (int k = 0; k < 6; ++k) { c[k] = s_hist[tid * 6 + k]; sum += c[k]; }
        int inc = sum;
        #pragma unroll
        for (int off = 1; off < 64; off <<= 1) {
            int v = __shfl_up(inc, off);
            if (lane >= off) inc += v;
        }
        int excl = inc - sum;
        #pragma unroll
        for (int k = 0; k < 6; ++k) {
            s_base[tid * 6 + k] = excl;
            s_cur[tid * 6 + k]  = excl;
            excl += c[k];
        }
        if (tid == 63) s_base[NBUCK] = excl;
    }
    __syncthreads();

    // ---- Phase A2: scatter keys into bucket regions (L2-hot reload, vectorized) ----
    for (int i = tid; i < N_ANCH / 4; i += 1024) {
        float4 v = sc4[i];
        float vv[4] = {v.x, v.y, v.z, v.w};
        #pragma unroll
        for (int k = 0; k < 4; ++k) {
            float sval = vv[k];
            if (sval > SCORE_THRESH) {
                int idx = i * 4 + k;
                int pos = atomicAdd(&s_cur[bucket_of(sval)], 1);
                if (pos < KCAND)
                    s_sorted[pos] = ((u64)__float_as_uint(sval) << 32)
                                  | (u64)(0xFFFFFFFFu - (unsigned)idx);
            }
        }
    }
    __syncthreads();

    // ---- per-bucket rank sort (one wave per bucket, no barriers inside) ----
    for (int bk = wv; bk < NBUCK; bk += 16) {
        int lo = s_base[bk], hi = s_base[bk + 1];
        if (lo > KCAND) lo = KCAND;
        if (hi > KCAND) hi = KCAND;
        int n = hi - lo;
        if (n <= 1) continue;
        u64 mykey = (lane < n) ? s_sorted[lo + lane] : 0ull;
        int rank = 0;
        for (int j = 0; j < n; ++j) {          // broadcast reads, conflict-free
            u64 kj = s_sorted[lo + j];
            rank += (kj > mykey);
        }
        if (lane < n) s_sorted[lo + rank] = mykey;  // in-wave: reads precede write
    }
    __syncthreads();

    int M = s_base[NBUCK]; if (M > KCAND) M = KCAND;

    // ---- pre-loop: decode pair 0 (128 candidates), zero parity-0 masks ----
    if (tid < 128) {
        s_pre[0][tid] = 0u; s_gmlo[0][tid] = 0u; s_gmhi[0][tid] = 0u;
        if (tid < M) {
            u64 key = s_sorted[tid];
            int idx = (int)(0xFFFFFFFFu - (unsigned)(key & 0xFFFFFFFFull));
            float4 bx = decode_one(anch4[idx], del4[idx]);
            s_cbox[0][tid]  = bx;
            s_carea[0][tid] = (bx.z - bx.x) * (bx.w - bx.y);
        }
    }
    __syncthreads();

    // ---- Phase B: greedy NMS, 128-candidate pairs (R6 region structure) ----
    // R1: wv1 decode/zero next; waves{0,2..15} long-loop both halves (branchless,
    //     unroll x2); waves 2..9 intra-half1.   bar
    // R2: wave0 resolve half1 || waves 9..15 intra-half2.   bar
    // R3: half2 vs new accepts (15 slices).   bar
    // R4: wave0 resolve half2.   bar
    int accCount = 0;
    for (int start = 0; start < M && accCount < NSEL; start += 128) {
        int p  = (start >> 7) & 1;
        int C  = M - start; if (C > 128) C = 128;
        int C1 = C < 64 ? C : 64;
        int C2 = C - C1;                       // candidates in half2 (0..64)
        int c  = lane;
        int sidx15 = (wv == 0) ? 0 : (wv - 1); // 15-slice id for waves {0,2..15}

        float4 c0 = make_float4(0.f,0.f,0.f,0.f), c1 = make_float4(0.f,0.f,0.f,0.f);
        float a0 = 0.f, a1 = 0.f;

        // ---------------- Region 1 ----------------
        if (wv == 1) {
            s_pre[p^1][c]       = 0u; s_pre[p^1][64+c]  = 0u;
            s_gmlo[p^1][c]      = 0u; s_gmlo[p^1][64+c] = 0u;
            s_gmhi[p^1][c]      = 0u; s_gmhi[p^1][64+c] = 0u;
            int ni0 = start + 128 + c;
            int ni1 = start + 192 + c;
            if (ni0 < M) {
                u64 key = s_sorted[ni0];
                int idx = (int)(0xFFFFFFFFu - (unsigned)(key & 0xFFFFFFFFull));
                float4 bx = decode_one(anch4[idx], del4[idx]);
                s_cbox[p^1][c]  = bx;
                s_carea[p^1][c] = (bx.z - bx.x) * (bx.w - bx.y);
            }
            if (ni1 < M) {
                u64 key = s_sorted[ni1];
                int idx = (int)(0xFFFFFFFFu - (unsigned)(key & 0xFFFFFFFFull));
                float4 bx = decode_one(anch4[idx], del4[idx]);
                s_cbox[p^1][64+c]  = bx;
                s_carea[p^1][64+c] = (bx.z - bx.x) * (bx.w - bx.y);
            }
        } else {
            // candidate registers (zero-box for invalid lanes: inter==0 always,
            // never suppressed, never triggers the uncertain band)
            if (c < C1) c0 = s_cbox[p][c];
            if (c < C2) c1 = s_cbox[p][64+c];
            a0 = (c0.z - c0.x) * (c0.w - c0.y);
            a1 = (c1.z - c1.x) * (c1.w - c1.y);

            // branchless long-loop, unroll x2 accepted: 2 box loads + 2 area
            // loads + 4 independent accumulation chains
            float m0 = -1.f, m1 = -1.f;
            int a = sidx15;
            for (; a + 15 < accCount; a += 30) {
                float4 A0 = s_accB[a];
                float4 A1 = s_accB[a + 15];
                float Aa0 = s_accA[a];
                float Aa1 = s_accA[a + 15];
                supp_acc(A0, Aa0, c0, a0, m0);
                supp_acc(A0, Aa0, c1, a1, m1);
                supp_acc(A1, Aa1, c0, a0, m0);
                supp_acc(A1, Aa1, c1, a1, m1);
            }
            if (a < accCount) {
                float4 A0 = s_accB[a];
                float Aa0 = s_accA[a];
                supp_acc(A0, Aa0, c0, a0, m0);
                supp_acc(A0, Aa0, c1, a1, m1);
            }
            bool s0 = (m0 >= 0.f), s1 = (m1 >= 0.f);
            bool rr = ((m0 < 0.f) && (m0 >= BAND)) || ((m1 < 0.f) && (m1 >= BAND));
            if (__builtin_expect(__any((int)rr), 0)) {
                for (int a2 = sidx15; a2 < accCount; a2 += 15) {
                    float4 A = s_accB[a2];
                    float Aa = s_accA[a2];
                    s0 |= supp_div(A, Aa, c0, a0);
                    s1 |= supp_div(A, Aa, c1, a1);
                }
            }
            if (s0 && c < C1) s_pre[p][c]      = 1u;   // same-value race, benign
            if (s1 && c < C2) s_pre[p][64 + c] = 1u;

            // intra half1: waves 2..9, 8 slices, branchless + deferred rerun
            if (wv >= 2 && wv <= 9 && c < C1) {
                int s8 = wv - 2;
                unsigned mlo = 0u, mhi = 0u;
                bool ur = false;
                for (int j = s8; j < c; j += 8) {        // j wave-uniform
                    float4 bj = s_cbox[p][j];
                    float  aj = s_carea[p][j];
                    bool sj, uj;
                    supp_bit(bj, aj, c0, a0, sj, uj);
                    ur |= uj;
                    unsigned bit = sj ? 1u : 0u;
                    if (j < 32) mlo |= bit << j; else mhi |= bit << (j - 32);
                }
                if (__builtin_expect(__any((int)ur), 0)) {
                    for (int j = s8; j < c; j += 8) {
                        float4 bj = s_cbox[p][j];
                        float  aj = s_carea[p][j];
                        unsigned bit = supp_div(bj, aj, c0, a0) ? 1u : 0u;
                        if (j < 32) mlo |= bit << j; else mhi |= bit << (j - 32);
                    }
                }
                if (mlo) atomicOr(&s_gmlo[p][c], mlo);
                if (mhi) atomicOr(&s_gmhi[p][c], mhi);
            }
        }
        __syncthreads();

        // ---------------- Region 2: resolve half1 || intra half2 ----------------
        if (tid < 64) {
            u64 mymask = ((u64)s_gmhi[p][tid] << 32) | (u64)s_gmlo[p][tid];
            bool alive = (tid < C1) && (s_pre[p][tid] == 0u);
            u64 accbits = 0ull, done = 0ull;
            int room = NSEL - accCount;
            int na = 0;
            while (na < room) {
                u64 am  = __ballot(alive);
                u64 rem = am & ~done;
                if (!rem) break;
                int l = __ffsll(rem) - 1;
                done = (2ull << l) - 1ull;
                accbits |= (1ull << l);
                ++na;
                if ((mymask >> l) & 1ull) alive = false;
            }
            if ((accbits >> tid) & 1ull) {
                int rank = __popcll(accbits & ((1ull << tid) - 1ull));
                float4 bx = s_cbox[p][tid];
                s_accB[accCount + rank] = bx;
                s_accA[accCount + rank] = (bx.z - bx.x) * (bx.w - bx.y);
            }
            if (tid == 0) s_accCount = accCount + __popcll(accbits);
        } else if (wv >= 9 && c < C2) {
            // intra half2: waves 9..15, 7 slices (overlaps the serial resolve)
            int s7 = wv - 9;
            unsigned mlo = 0u, mhi = 0u;
            bool ur = false;
            for (int jj = s7; jj < c; jj += 7) {
                float4 bj = s_cbox[p][64 + jj];
                float  aj = s_carea[p][64 + jj];
                bool sj, uj;
                supp_bit(bj, aj, c1, a1, sj, uj);
                ur |= uj;
                unsigned bit = sj ? 1u : 0u;
                if (jj < 32) mlo |= bit << jj; else mhi |= bit << (jj - 32);
            }
            if (__builtin_expect(__any((int)ur), 0)) {
                for (int jj = s7; jj < c; jj += 7) {
                    float4 bj = s_cbox[p][64 + jj];
                    float  aj = s_carea[p][64 + jj];
                    unsigned bit = supp_div(bj, aj, c1, a1) ? 1u : 0u;
                    if (jj < 32) mlo |= bit << jj; else mhi |= bit << (jj - 32);
                }
            }
            if (mlo) atomicOr(&s_gmlo[p][64 + c], mlo);
            if (mhi) atomicOr(&s_gmhi[p][64 + c], mhi);
        }
        __syncthreads();
        int acc1 = s_accCount;

        // ---------------- Region 3: half2 vs half1's new accepts ----------------
        if (wv != 1) {
            float m1b = -1.f;
            for (int a3 = accCount + sidx15; a3 < acc1; a3 += 15) {
                float4 A = s_accB[a3];
                float Aa = s_accA[a3];
                supp_acc(A, Aa, c1, a1, m1b);
            }
            bool s1b = (m1b >= 0.f);
            bool rr  = (m1b < 0.f) && (m1b >= BAND);
            if (__builtin_expect(__any((int)rr), 0)) {
                for (int a3 = accCount + sidx15; a3 < acc1; a3 += 15) {
                    float4 A = s_accB[a3];
                    float Aa = s_accA[a3];
                    s1b |= supp_div(A, Aa, c1, a1);
                }
            }
            if (s1b && c < C2) s_pre[p][64 + c] = 1u;
        }
        __syncthreads();

        // ---------------- Region 4: resolve half2 ----------------
        if (tid < 64) {
            u64 mymask = ((u64)s_gmhi[p][64+tid] << 32) | (u64)s_gmlo[p][64+tid];
            bool alive = (tid < C2) && (s_pre[p][64+tid] == 0u);
            u64 accbits = 0ull, done = 0ull;
            int room = NSEL - acc1;
            int na = 0;
            while (na < room) {
                u64 am  = __ballot(alive);
                u64 rem = am & ~done;
                if (!rem) break;
                int l = __ffsll(rem) - 1;
                done = (2ull << l) - 1ull;
                accbits |= (1ull << l);
                ++na;
                if ((mymask >> l) & 1ull) alive = false;
            }
            if ((accbits >> tid) & 1ull) {
                int rank = __popcll(accbits & ((1ull << tid) - 1ull));
                float4 bx = s_cbox[p][64+tid];
                s_accB[acc1 + rank] = bx;
                s_accA[acc1 + rank] = (bx.z - bx.x) * (bx.w - bx.y);
            }
            if (tid == 0) s_accCount = acc1 + __popcll(accbits);
        }
        __syncthreads();
        accCount = s_accCount;
    }

    // ---- Phase C: select_rois ----
    if (tid < NGT) s_gt[tid] = gt4[tid];
    __syncthreads();

    if (tid < NSEL) {
        float4 bx;
        if (tid < accCount) {
            float4 r = s_accB[tid];
            bx = make_float4(clip01(r.x), clip01(r.y), clip01(r.z), clip01(r.w));
        } else bx = make_float4(0.f, 0.f, 0.f, 0.f);
        float aa = (bx.z - bx.x) * (bx.w - bx.y);
        float best = -1e38f; int bi = 0;
        for (int g = 0; g < NGT; ++g) {
            float4 gb = s_gt[g];
            float y1 = fmaxf(bx.x, gb.x);
            float x1 = fmaxf(bx.y, gb.y);
            float y2 = fminf(bx.z, gb.z);
            float x2 = fminf(bx.w, gb.w);
            float ih = fmaxf(y2 - y1, 0.0f);
            float iw = fmaxf(x2 - x1, 0.0f);
            float inter = ih * iw;
            float ab = (gb.z - gb.x) * (gb.w - gb.y);
            float iou = inter / (aa + ab - inter + 1e-7f);
            if (iou > best) { best = iou; bi = g; }   // first-occurrence argmax
        }
        s_merged[tid] = best;
        s_gtbest[tid] = bi;
    }
    __syncthreads();

    // stable top-64 via rank selection: rank = #{j: v_j > v_i || (v_j==v_i && j<i)}
    if (tid < NSEL) {
        float v = s_merged[tid];
        int rank = 0;
        for (int j = 0; j < NSEL; ++j) {
            float u = s_merged[j];
            rank += (u > v) || (u == v && j < tid);
        }
        if (rank < 64) s_selidx[rank] = tid;
    }
    __syncthreads();

    // ---- outputs ----
    float* outIdx = out + (size_t)NBATCH * 128 * 4;   // 8192 box floats first
    if (tid < 256) {
        int r = tid >> 2, cc = tid & 3;
        int i = s_selidx[r];
        float val = 0.0f;
        if (i < accCount) {
            const float* p = (const float*)&s_accB[i];
            val = clip01(p[cc]);
        }
        out[((size_t)b * 128 + r) * 4 + cc] = val;
    } else if (tid < 512) {
        int j = tid - 256;
        out[((size_t)b * 128 + 64) * 4 + j] = 0.0f;   // TOTAL_NEG zero boxes
    } else if (tid < 576) {
        int r = tid - 512;
        outIdx[b * 64 + r] = (float)s_gtbest[s_selidx[r]];
    }
}

extern "C" void kernel_launch(void* const* d_in, const int* in_sizes, int n_in,
                              void* d_out, int out_size, void* d_ws, size_t ws_size,
                              hipStream_t stream) {
    const float* deltas  = (const float*)d_in[0];
    const float* labels  = (const float*)d_in[1];
    const float* anchors = (const float*)d_in[2];
    const float* gt      = (const float*)d_in[3];
    float* out = (float*)d_out;
    roi_bbox_kernel<<<NBATCH, 1024, 0, stream>>>(deltas, labels, anchors, gt, out);
}